// Round 2
// baseline (1046.050 us; speedup 1.0000x reference)
//
#include <hip/hip_runtime.h>
#include <hip/hip_bf16.h>

#define NN 20000
#define DD 512
#define EE 150000

typedef __attribute__((ext_vector_type(8))) short short8;
typedef __attribute__((ext_vector_type(4))) float floatx4;

static __device__ __forceinline__ float bfbits2f(unsigned short u) {
    unsigned int x = ((unsigned int)u) << 16;
    return __uint_as_float(x);
}

#define GLOAD_LDS16(g, l)                                                        \
    __builtin_amdgcn_global_load_lds((const __attribute__((address_space(1))) void*)(g), \
                                     (__attribute__((address_space(3))) void*)(l), 16, 0, 0)

// ---------------- convert fp32 -> bf16 (vectorized) ----------------
__global__ __launch_bounds__(256) void k_convert_bf16(const float* __restrict__ in,
                                                      __hip_bfloat16* __restrict__ out, int n4) {
    int i = blockIdx.x * blockDim.x + threadIdx.x;
    if (i >= n4) return;
    float4 v = ((const float4*)in)[i];
    union { __hip_bfloat16 b[4]; ushort4 u; } cv;
    cv.b[0] = __float2bfloat16(v.x);
    cv.b[1] = __float2bfloat16(v.y);
    cv.b[2] = __float2bfloat16(v.z);
    cv.b[3] = __float2bfloat16(v.w);
    *(ushort4*)(out + 4l * i) = cv.u;
}

// ---------------- 512x512 transpose + convert to bf16 ----------------
__global__ __launch_bounds__(1024) void k_transpose_bf16(const float* __restrict__ in,
                                                         __hip_bfloat16* __restrict__ out) {
    __shared__ float tile[32][33];
    int bx = blockIdx.x * 32;
    int by = blockIdx.y * 32;
    int tx = threadIdx.x, ty = threadIdx.y;
    tile[ty][tx] = in[(by + ty) * 512 + bx + tx];
    __syncthreads();
    out[(bx + ty) * 512 + by + tx] = __float2bfloat16(tile[tx][ty]);
}

// ---------------- m97-style bf16 MFMA GEMM: C[M,512] = A[M,512] @ B ----------------
// Bt[n][k] = B[k][n] bf16. 128x128 tile, 4 waves (2x2 of 64x64), BK=32,
// global_load_lds width-16 staging (lane-linear LDS layout, no padding).
// mode 0: Cb = bf16(C). mode 1: Cf = relu(C + addend). mode 2: Cf = C.
__global__ __launch_bounds__(256)
void k_gemm128(const __hip_bfloat16* __restrict__ A, const __hip_bfloat16* __restrict__ Bt,
               float* __restrict__ Cf, __hip_bfloat16* __restrict__ Cb,
               const float* __restrict__ addend, int M, int mode) {
    // LDS 16B-block i (i=0..511) holds tile[(r = i&127)][k-block (q = i>>7)]
    __shared__ __hip_bfloat16 As[4096];
    __shared__ __hip_bfloat16 Bs[4096];
    const int tid = threadIdx.x;
    const int lane = tid & 63;
    const int wave = tid >> 6;
    const int row0 = blockIdx.x * 128;
    const int col0 = blockIdx.y * 128;
    const int wm = (wave >> 1) * 64;
    const int wn = (wave & 1) * 64;
    const int q = lane >> 4;
    const int l15 = lane & 15;

    // staging addresses: thread t covers LDS blocks t (q=tid>>7) and 256+t (q+2)
    const int sr = tid & 127;
    const int sq = tid >> 7;
    int garow = row0 + sr;
    if (garow >= M) garow = M - 1;
    const __hip_bfloat16* aptr = A + (size_t)garow * DD + sq * 8;
    const __hip_bfloat16* bptr = Bt + (size_t)(col0 + sr) * DD + sq * 8;
    __hip_bfloat16* alds0 = As + (size_t)tid * 8;
    __hip_bfloat16* alds1 = As + (size_t)(256 + tid) * 8;
    __hip_bfloat16* blds0 = Bs + (size_t)tid * 8;
    __hip_bfloat16* blds1 = Bs + (size_t)(256 + tid) * 8;

    floatx4 acc[4][4];
#pragma unroll
    for (int a = 0; a < 4; a++)
#pragma unroll
        for (int b = 0; b < 4; b++) acc[a][b] = (floatx4){0.f, 0.f, 0.f, 0.f};

    for (int k0 = 0; k0 < DD; k0 += 32) {
        __syncthreads();  // prior iteration's ds_reads done before overwrite
        GLOAD_LDS16(aptr, alds0);
        GLOAD_LDS16(aptr + 16, alds1);  // +16 elem = +32B => q+2 k-block
        GLOAD_LDS16(bptr, blds0);
        GLOAD_LDS16(bptr + 16, blds1);
        aptr += 32;
        bptr += 32;
        __syncthreads();  // compiler drains vmcnt before barrier
        short8 af[4], bf[4];
#pragma unroll
        for (int mi = 0; mi < 4; mi++)
            af[mi] = *(const short8*)(As + ((size_t)q * 128 + wm + mi * 16 + l15) * 8);
#pragma unroll
        for (int ni = 0; ni < 4; ni++)
            bf[ni] = *(const short8*)(Bs + ((size_t)q * 128 + wn + ni * 16 + l15) * 8);
#pragma unroll
        for (int mi = 0; mi < 4; mi++)
#pragma unroll
            for (int ni = 0; ni < 4; ni++)
                acc[mi][ni] =
                    __builtin_amdgcn_mfma_f32_16x16x32_bf16(af[mi], bf[ni], acc[mi][ni], 0, 0, 0);
    }

#pragma unroll
    for (int mi = 0; mi < 4; mi++)
#pragma unroll
        for (int ni = 0; ni < 4; ni++)
#pragma unroll
            for (int r = 0; r < 4; r++) {
                int grow = row0 + wm + mi * 16 + q * 4 + r;
                int gcol = col0 + wn + ni * 16 + l15;
                if (grow < M) {
                    float v = acc[mi][ni][r];
                    size_t idx = (size_t)grow * DD + gcol;
                    if (mode == 0) Cb[idx] = __float2bfloat16(v);
                    else if (mode == 1) {
                        v += addend[idx];
                        Cf[idx] = v > 0.f ? v : 0.f;
                    } else Cf[idx] = v;
                }
            }
}

// ---------------- el/er: per-row dot products ----------------
__global__ __launch_bounds__(256)
void k_el_er(const __hip_bfloat16* __restrict__ h, const float* __restrict__ al,
             const float* __restrict__ ar, float* __restrict__ el, float* __restrict__ er) {
    int wave = threadIdx.x >> 6, lane = threadIdx.x & 63;
    int row = blockIdx.x * 4 + wave;
    if (row >= NN) return;
    uint4 hv = *(const uint4*)(h + (size_t)row * 512 + lane * 8);
    const unsigned short* hs = (const unsigned short*)&hv;
    float4 a0 = *(const float4*)(al + lane * 8);
    float4 a1 = *(const float4*)(al + lane * 8 + 4);
    float4 r0 = *(const float4*)(ar + lane * 8);
    float4 r1 = *(const float4*)(ar + lane * 8 + 4);
    float hf[8];
#pragma unroll
    for (int j = 0; j < 8; j++) hf[j] = bfbits2f(hs[j]);
    float sl = hf[0] * a0.x + hf[1] * a0.y + hf[2] * a0.z + hf[3] * a0.w +
               hf[4] * a1.x + hf[5] * a1.y + hf[6] * a1.z + hf[7] * a1.w;
    float sr = hf[0] * r0.x + hf[1] * r0.y + hf[2] * r0.z + hf[3] * r0.w +
               hf[4] * r1.x + hf[5] * r1.y + hf[6] * r1.z + hf[7] * r1.w;
#pragma unroll
    for (int off = 32; off > 0; off >>= 1) {
        sl += __shfl_down(sl, off);
        sr += __shfl_down(sr, off);
    }
    if (lane == 0) {
        el[row] = sl;
        er[row] = sr;
    }
}

// ---------------- CSR build ----------------
__global__ void k_zero_i32(int* p, int n) {
    int i = blockIdx.x * blockDim.x + threadIdx.x;
    if (i < n) p[i] = 0;
}

__global__ void k_count(const int* __restrict__ edges, int* __restrict__ deg) {
    int e = blockIdx.x * blockDim.x + threadIdx.x;
    if (e < EE) atomicAdd(&deg[edges[EE + e]], 1);
}

__global__ __launch_bounds__(1024)
void k_scan(const int* __restrict__ deg, int* __restrict__ row_ptr, int* __restrict__ cursor) {
    __shared__ int sm[1024];
    int t = threadIdx.x;
    const int CH = 20;
    int begin = t * CH;
    int end = begin + CH;
    if (end > NN) end = NN;
    int s = 0;
    if (begin < NN)
        for (int i = begin; i < end; i++) s += deg[i];
    sm[t] = s;
    __syncthreads();
    for (int off = 1; off < 1024; off <<= 1) {
        int v = (t >= off) ? sm[t - off] : 0;
        __syncthreads();
        sm[t] += v;
        __syncthreads();
    }
    int run = sm[t] - s;
    if (begin < NN) {
        for (int i = begin; i < end; i++) {
            row_ptr[i] = run;
            cursor[i] = run;
            run += deg[i];
        }
        if (end == NN) row_ptr[NN] = run;
    }
}

__global__ void k_scatter(const int* __restrict__ edges, int* __restrict__ cursor,
                          int* __restrict__ csr_src) {
    int e = blockIdx.x * blockDim.x + threadIdx.x;
    if (e < EE) {
        int dst = edges[EE + e];
        int pos = atomicAdd(&cursor[dst], 1);
        csr_src[pos] = edges[e];
    }
}

// ---------------- wave-per-dst edge softmax -> alpha ----------------
__global__ __launch_bounds__(256)
void k_alpha_wave(const int* __restrict__ row_ptr, const int* __restrict__ csr_src,
                  const float* __restrict__ el, const float* __restrict__ er,
                  float* __restrict__ alpha) {
    int d = (blockIdx.x * blockDim.x + threadIdx.x) >> 6;
    int lane = threadIdx.x & 63;
    if (d >= NN) return;
    int s0 = row_ptr[d], s1 = row_ptr[d + 1];
    int deg = s1 - s0;
    if (deg == 0) return;
    float erd = er[d];
    if (deg <= 64) {
        float v = -1e30f;
        int j = s0 + lane;
        if (lane < deg) {
            float e = el[csr_src[j]] + erd;
            v = e >= 0.f ? e : 0.2f * e;
        }
        float m = v;
#pragma unroll
        for (int off = 32; off > 0; off >>= 1) m = fmaxf(m, __shfl_xor(m, off));
        float w = (lane < deg) ? __expf(v - m) : 0.f;
        float s = w;
#pragma unroll
        for (int off = 32; off > 0; off >>= 1) s += __shfl_xor(s, off);
        if (lane < deg) alpha[j] = w / s;
    } else {
        float m = -1e30f;
        for (int j = s0 + lane; j < s1; j += 64) {
            float e = el[csr_src[j]] + erd;
            e = e >= 0.f ? e : 0.2f * e;
            alpha[j] = e;
            m = fmaxf(m, e);
        }
#pragma unroll
        for (int off = 32; off > 0; off >>= 1) m = fmaxf(m, __shfl_xor(m, off));
        float s = 0.f;
        for (int j = s0 + lane; j < s1; j += 64) {
            float w = __expf(alpha[j] - m);
            alpha[j] = w;
            s += w;
        }
#pragma unroll
        for (int off = 32; off > 0; off >>= 1) s += __shfl_xor(s, off);
        float inv = 1.f / s;
        for (int j = s0 + lane; j < s1; j += 64) alpha[j] *= inv;
    }
}

// ---------------- wave-per-dst aggregate: t[dst] = sum alpha*h[src] (+prev)+bias ----------------
__global__ __launch_bounds__(256)
void k_aggregate_wave(const int* __restrict__ row_ptr, const int* __restrict__ csr_src,
                      const float* __restrict__ alpha, const __hip_bfloat16* __restrict__ h,
                      const float* __restrict__ out_prev, const float* __restrict__ bias,
                      __hip_bfloat16* __restrict__ t_out, int use_prev) {
    int d = (blockIdx.x * blockDim.x + threadIdx.x) >> 6;
    int lane = threadIdx.x & 63;
    if (d >= NN) return;
    int s0 = row_ptr[d], s1 = row_ptr[d + 1];
    int deg = s1 - s0;
    int base = lane * 8;
    float acc[8] = {0.f, 0.f, 0.f, 0.f, 0.f, 0.f, 0.f, 0.f};
    for (int j0 = 0; j0 < deg; j0 += 64) {
        int cnt = deg - j0;
        if (cnt > 64) cnt = 64;
        int sv = 0;
        float av = 0.f;
        if (lane < cnt) {
            sv = csr_src[s0 + j0 + lane];
            av = alpha[s0 + j0 + lane];
        }
        for (int t = 0; t < cnt; t++) {
            int s = __shfl(sv, t);
            float a = __shfl(av, t);
            uint4 hv = *(const uint4*)(h + (size_t)s * DD + base);
            const unsigned short* hs = (const unsigned short*)&hv;
#pragma unroll
            for (int k = 0; k < 8; k++) acc[k] += a * bfbits2f(hs[k]);
        }
    }
    if (use_prev) {
        float4 p0 = *(const float4*)(out_prev + (size_t)d * DD + base);
        float4 p1 = *(const float4*)(out_prev + (size_t)d * DD + base + 4);
        acc[0] += p0.x; acc[1] += p0.y; acc[2] += p0.z; acc[3] += p0.w;
        acc[4] += p1.x; acc[5] += p1.y; acc[6] += p1.z; acc[7] += p1.w;
    }
    float4 b0 = *(const float4*)(bias + base);
    float4 b1 = *(const float4*)(bias + base + 4);
    acc[0] += b0.x; acc[1] += b0.y; acc[2] += b0.z; acc[3] += b0.w;
    acc[4] += b1.x; acc[5] += b1.y; acc[6] += b1.z; acc[7] += b1.w;
    union { __hip_bfloat16 b[8]; uint4 u; } cv;
#pragma unroll
    for (int k = 0; k < 8; k++) cv.b[k] = __float2bfloat16(acc[k]);
    *(uint4*)(t_out + (size_t)d * DD + base) = cv.u;
}

extern "C" void kernel_launch(void* const* d_in, const int* in_sizes, int n_in,
                              void* d_out, int out_size, void* d_ws, size_t ws_size,
                              hipStream_t stream) {
    const float* x = (const float*)d_in[0];
    const int* edges[4] = {(const int*)d_in[1], (const int*)d_in[5], (const int*)d_in[9],
                           (const int*)d_in[13]};
    const float* W[4] = {(const float*)d_in[2], (const float*)d_in[6], (const float*)d_in[10],
                         (const float*)d_in[14]};
    const float* al[4] = {(const float*)d_in[3], (const float*)d_in[7], (const float*)d_in[11],
                          (const float*)d_in[15]};
    const float* ar[4] = {(const float*)d_in[4], (const float*)d_in[8], (const float*)d_in[12],
                          (const float*)d_in[16]};
    const float* Wl = (const float*)d_in[17];
    const float* bias = (const float*)d_in[18];
    float* out = (float*)d_out;

    char* w = (char*)d_ws;
    auto alloc = [&](size_t bytes) {
        char* p = w;
        w += (bytes + 255) & ~(size_t)255;
        return p;
    };
    __hip_bfloat16* x_bf = (__hip_bfloat16*)alloc((size_t)NN * DD * 2);
    __hip_bfloat16* h_bf = (__hip_bfloat16*)alloc((size_t)NN * DD * 2);
    __hip_bfloat16* t_bf = (__hip_bfloat16*)alloc((size_t)NN * DD * 2);
    float* xWl = (float*)alloc((size_t)NN * DD * 4);
    __hip_bfloat16* Wt[4];
    for (int i = 0; i < 4; i++) Wt[i] = (__hip_bfloat16*)alloc((size_t)DD * DD * 2);
    __hip_bfloat16* WlTt = (__hip_bfloat16*)alloc((size_t)DD * DD * 2);
    __hip_bfloat16* WlTb = (__hip_bfloat16*)alloc((size_t)DD * DD * 2);
    float* el = (float*)alloc((size_t)NN * 4);
    float* er = (float*)alloc((size_t)NN * 4);
    int* deg = (int*)alloc((size_t)NN * 4);
    int* row_ptr = (int*)alloc((size_t)(NN + 1) * 4);
    int* cursor = (int*)alloc((size_t)NN * 4);
    int* csr_src = (int*)alloc((size_t)EE * 4);
    float* alphaw = (float*)alloc((size_t)EE * 4);

    // one-time preprocessing
    k_convert_bf16<<<(NN * DD / 4 + 255) / 256, 256, 0, stream>>>(x, x_bf, NN * DD / 4);
    dim3 tb(32, 32), tg(16, 16);
    for (int i = 0; i < 4; i++) k_transpose_bf16<<<tg, tb, 0, stream>>>(W[i], Wt[i]);
    k_transpose_bf16<<<tg, tb, 0, stream>>>(Wl, WlTt);
    k_transpose_bf16<<<tg, tb, 0, stream>>>(Wl + 512 * 512, WlTb);

    dim3 gg((NN + 127) / 128, 4);
    // xWl = x @ Wl_top (loop-invariant)
    k_gemm128<<<gg, 256, 0, stream>>>(x_bf, WlTt, xWl, nullptr, nullptr, NN, 2);

    for (int i = 0; i < 4; i++) {
        // h = x @ W_i (bf16 out)
        k_gemm128<<<gg, 256, 0, stream>>>(x_bf, Wt[i], nullptr, h_bf, nullptr, NN, 0);
        k_el_er<<<NN / 4, 256, 0, stream>>>(h_bf, al[i], ar[i], el, er);
        // CSR build
        k_zero_i32<<<(NN + 255) / 256, 256, 0, stream>>>(deg, NN);
        k_count<<<(EE + 255) / 256, 256, 0, stream>>>(edges[i], deg);
        k_scan<<<1, 1024, 0, stream>>>(deg, row_ptr, cursor);
        k_scatter<<<(EE + 255) / 256, 256, 0, stream>>>(edges[i], cursor, csr_src);
        // edge softmax (wave per dst)
        k_alpha_wave<<<(NN * 64 + 255) / 256, 256, 0, stream>>>(row_ptr, csr_src, el, er, alphaw);
        // aggregate + prev + bias -> t (bf16), wave per dst
        k_aggregate_wave<<<(NN * 64 + 255) / 256, 256, 0, stream>>>(row_ptr, csr_src, alphaw, h_bf,
                                                                    out, bias, t_bf, i > 0 ? 1 : 0);
        // out = relu(xWl + t @ Wl_bot)
        k_gemm128<<<gg, 256, 0, stream>>>(t_bf, WlTb, out, nullptr, xWl, NN, 1);
    }
}

// Round 3
// 900.827 us; speedup vs baseline: 1.1612x; 1.1612x over previous
//
#include <hip/hip_runtime.h>
#include <hip/hip_bf16.h>

#define NN 20000
#define DD 512
#define EE 150000

typedef __attribute__((ext_vector_type(8))) short short8;
typedef __attribute__((ext_vector_type(4))) float floatx4;

static __device__ __forceinline__ float bfbits2f(unsigned short u) {
    unsigned int x = ((unsigned int)u) << 16;
    return __uint_as_float(x);
}

#define GLOAD_LDS16(g, l)                                                        \
    __builtin_amdgcn_global_load_lds((const __attribute__((address_space(1))) void*)(g), \
                                     (__attribute__((address_space(3))) void*)(l), 16, 0, 0)

// ---------------- convert fp32 -> bf16 (vectorized) ----------------
__global__ __launch_bounds__(256) void k_convert_bf16(const float* __restrict__ in,
                                                      __hip_bfloat16* __restrict__ out, int n4) {
    int i = blockIdx.x * blockDim.x + threadIdx.x;
    if (i >= n4) return;
    float4 v = ((const float4*)in)[i];
    union { __hip_bfloat16 b[4]; ushort4 u; } cv;
    cv.b[0] = __float2bfloat16(v.x);
    cv.b[1] = __float2bfloat16(v.y);
    cv.b[2] = __float2bfloat16(v.z);
    cv.b[3] = __float2bfloat16(v.w);
    *(ushort4*)(out + 4l * i) = cv.u;
}

// ---------------- 512x512 transpose + convert to bf16 ----------------
__global__ __launch_bounds__(1024) void k_transpose_bf16(const float* __restrict__ in,
                                                         __hip_bfloat16* __restrict__ out) {
    __shared__ float tile[32][33];
    int bx = blockIdx.x * 32;
    int by = blockIdx.y * 32;
    int tx = threadIdx.x, ty = threadIdx.y;
    tile[ty][tx] = in[(by + ty) * 512 + bx + tx];
    __syncthreads();
    out[(bx + ty) * 512 + by + tx] = __float2bfloat16(tile[tx][ty]);
}

// ---------------- bf16 MFMA GEMM: C[M,512] = A[M,512] @ B ----------------
// 64 rows x 128 cols tile -> grid (313,4)=1252 blocks (occupancy is king for
// this skinny GEMM; round-2's 128x128/628-block version ran 1 block/CU and
// was latency-bound at 82us). global_load_lds width-16 staging, lane-linear
// LDS layout [kblock][row] so fragment ds_read_b128 is conflict-free.
// mode 0: Cb = bf16(C). mode 1: Cf = relu(C + addend). mode 2: Cf = C.
__global__ __launch_bounds__(256)
void k_gemm(const __hip_bfloat16* __restrict__ A, const __hip_bfloat16* __restrict__ Bt,
            float* __restrict__ Cf, __hip_bfloat16* __restrict__ Cb,
            const float* __restrict__ addend, int M, int mode) {
    __shared__ __hip_bfloat16 As[64 * 32];   // 4 KB: 16B-block i = [q=i>>6][r=i&63]
    __shared__ __hip_bfloat16 Bs[128 * 32];  // 8 KB: 16B-block i = [q=i>>7][r=i&127]
    const int tid = threadIdx.x;
    const int lane = tid & 63;
    const int wave = tid >> 6;
    const int row0 = blockIdx.x * 64;
    const int col0 = blockIdx.y * 128;
    const int wm = (wave >> 1) * 32;   // wave rows: 0 or 32
    const int wn = (wave & 1) * 64;    // wave cols: 0 or 64
    const int q = lane >> 4;
    const int l15 = lane & 15;

    // A staging: thread t covers 16B-block t  (q=t>>6, r=t&63)
    int ar = row0 + (tid & 63);
    if (ar >= M) ar = M - 1;
    const __hip_bfloat16* aptr = A + (size_t)ar * DD + (tid >> 6) * 8;
    __hip_bfloat16* alds = As + (size_t)tid * 8;
    // B staging: thread t covers 16B-blocks t and 256+t
    const int brow = col0 + (tid & 127);
    const __hip_bfloat16* bptr0 = Bt + (size_t)brow * DD + (tid >> 7) * 8;
    const __hip_bfloat16* bptr1 = Bt + (size_t)brow * DD + (2 + (tid >> 7)) * 8;
    __hip_bfloat16* blds0 = Bs + (size_t)tid * 8;
    __hip_bfloat16* blds1 = Bs + (size_t)(256 + tid) * 8;

    floatx4 acc[2][4];
#pragma unroll
    for (int a = 0; a < 2; a++)
#pragma unroll
        for (int b = 0; b < 4; b++) acc[a][b] = (floatx4){0.f, 0.f, 0.f, 0.f};

    for (int k0 = 0; k0 < DD; k0 += 32) {
        __syncthreads();  // prior iteration's ds_reads done before overwrite
        GLOAD_LDS16(aptr, alds);
        GLOAD_LDS16(bptr0, blds0);
        GLOAD_LDS16(bptr1, blds1);
        aptr += 32;
        bptr0 += 32;
        bptr1 += 32;
        __syncthreads();  // vmcnt drained by compiler before barrier
        short8 af[2], bf[4];
#pragma unroll
        for (int mi = 0; mi < 2; mi++)
            af[mi] = *(const short8*)(As + ((size_t)q * 64 + wm + mi * 16 + l15) * 8);
#pragma unroll
        for (int ni = 0; ni < 4; ni++)
            bf[ni] = *(const short8*)(Bs + ((size_t)q * 128 + wn + ni * 16 + l15) * 8);
#pragma unroll
        for (int mi = 0; mi < 2; mi++)
#pragma unroll
            for (int ni = 0; ni < 4; ni++)
                acc[mi][ni] =
                    __builtin_amdgcn_mfma_f32_16x16x32_bf16(af[mi], bf[ni], acc[mi][ni], 0, 0, 0);
    }

#pragma unroll
    for (int mi = 0; mi < 2; mi++)
#pragma unroll
        for (int ni = 0; ni < 4; ni++)
#pragma unroll
            for (int r = 0; r < 4; r++) {
                int grow = row0 + wm + mi * 16 + q * 4 + r;
                int gcol = col0 + wn + ni * 16 + l15;
                if (grow < M) {
                    float v = acc[mi][ni][r];
                    size_t idx = (size_t)grow * DD + gcol;
                    if (mode == 0) Cb[idx] = __float2bfloat16(v);
                    else if (mode == 1) {
                        v += addend[idx];
                        Cf[idx] = v > 0.f ? v : 0.f;
                    } else Cf[idx] = v;
                }
            }
}

// ---------------- el/er: per-row dot products ----------------
__global__ __launch_bounds__(256)
void k_el_er(const __hip_bfloat16* __restrict__ h, const float* __restrict__ al,
             const float* __restrict__ ar, float* __restrict__ el, float* __restrict__ er) {
    int wave = threadIdx.x >> 6, lane = threadIdx.x & 63;
    int row = blockIdx.x * 4 + wave;
    if (row >= NN) return;
    uint4 hv = *(const uint4*)(h + (size_t)row * 512 + lane * 8);
    const unsigned short* hs = (const unsigned short*)&hv;
    float4 a0 = *(const float4*)(al + lane * 8);
    float4 a1 = *(const float4*)(al + lane * 8 + 4);
    float4 r0 = *(const float4*)(ar + lane * 8);
    float4 r1 = *(const float4*)(ar + lane * 8 + 4);
    float hf[8];
#pragma unroll
    for (int j = 0; j < 8; j++) hf[j] = bfbits2f(hs[j]);
    float sl = hf[0] * a0.x + hf[1] * a0.y + hf[2] * a0.z + hf[3] * a0.w +
               hf[4] * a1.x + hf[5] * a1.y + hf[6] * a1.z + hf[7] * a1.w;
    float sr = hf[0] * r0.x + hf[1] * r0.y + hf[2] * r0.z + hf[3] * r0.w +
               hf[4] * r1.x + hf[5] * r1.y + hf[6] * r1.z + hf[7] * r1.w;
#pragma unroll
    for (int off = 32; off > 0; off >>= 1) {
        sl += __shfl_down(sl, off);
        sr += __shfl_down(sr, off);
    }
    if (lane == 0) {
        el[row] = sl;
        er[row] = sr;
    }
}

// ---------------- CSR build ----------------
__global__ void k_zero_i32(int* p, int n) {
    int i = blockIdx.x * blockDim.x + threadIdx.x;
    if (i < n) p[i] = 0;
}

__global__ void k_count(const int* __restrict__ edges, int* __restrict__ deg) {
    int e = blockIdx.x * blockDim.x + threadIdx.x;
    if (e < EE) atomicAdd(&deg[edges[EE + e]], 1);
}

__global__ __launch_bounds__(1024)
void k_scan(const int* __restrict__ deg, int* __restrict__ row_ptr, int* __restrict__ cursor) {
    __shared__ int sm[1024];
    int t = threadIdx.x;
    const int CH = 20;
    int begin = t * CH;
    int end = begin + CH;
    if (end > NN) end = NN;
    int s = 0;
    if (begin < NN)
        for (int i = begin; i < end; i++) s += deg[i];
    sm[t] = s;
    __syncthreads();
    for (int off = 1; off < 1024; off <<= 1) {
        int v = (t >= off) ? sm[t - off] : 0;
        __syncthreads();
        sm[t] += v;
        __syncthreads();
    }
    int run = sm[t] - s;
    if (begin < NN) {
        for (int i = begin; i < end; i++) {
            row_ptr[i] = run;
            cursor[i] = run;
            run += deg[i];
        }
        if (end == NN) row_ptr[NN] = run;
    }
}

__global__ void k_scatter(const int* __restrict__ edges, int* __restrict__ cursor,
                          int* __restrict__ csr_src) {
    int e = blockIdx.x * blockDim.x + threadIdx.x;
    if (e < EE) {
        int dst = edges[EE + e];
        int pos = atomicAdd(&cursor[dst], 1);
        csr_src[pos] = edges[e];
    }
}

// ---------------- wave-per-dst edge softmax -> alpha ----------------
__global__ __launch_bounds__(256)
void k_alpha_wave(const int* __restrict__ row_ptr, const int* __restrict__ csr_src,
                  const float* __restrict__ el, const float* __restrict__ er,
                  float* __restrict__ alpha) {
    int d = (blockIdx.x * blockDim.x + threadIdx.x) >> 6;
    int lane = threadIdx.x & 63;
    if (d >= NN) return;
    int s0 = row_ptr[d], s1 = row_ptr[d + 1];
    int deg = s1 - s0;
    if (deg == 0) return;
    float erd = er[d];
    if (deg <= 64) {
        float v = -1e30f;
        int j = s0 + lane;
        if (lane < deg) {
            float e = el[csr_src[j]] + erd;
            v = e >= 0.f ? e : 0.2f * e;
        }
        float m = v;
#pragma unroll
        for (int off = 32; off > 0; off >>= 1) m = fmaxf(m, __shfl_xor(m, off));
        float w = (lane < deg) ? __expf(v - m) : 0.f;
        float s = w;
#pragma unroll
        for (int off = 32; off > 0; off >>= 1) s += __shfl_xor(s, off);
        if (lane < deg) alpha[j] = w / s;
    } else {
        float m = -1e30f;
        for (int j = s0 + lane; j < s1; j += 64) {
            float e = el[csr_src[j]] + erd;
            e = e >= 0.f ? e : 0.2f * e;
            alpha[j] = e;
            m = fmaxf(m, e);
        }
#pragma unroll
        for (int off = 32; off > 0; off >>= 1) m = fmaxf(m, __shfl_xor(m, off));
        float s = 0.f;
        for (int j = s0 + lane; j < s1; j += 64) {
            float w = __expf(alpha[j] - m);
            alpha[j] = w;
            s += w;
        }
#pragma unroll
        for (int off = 32; off > 0; off >>= 1) s += __shfl_xor(s, off);
        float inv = 1.f / s;
        for (int j = s0 + lane; j < s1; j += 64) alpha[j] *= inv;
    }
}

// ---------------- wave-per-dst aggregate: t[dst] = sum alpha*h[src] (+prev)+bias ----------------
__global__ __launch_bounds__(256)
void k_aggregate_wave(const int* __restrict__ row_ptr, const int* __restrict__ csr_src,
                      const float* __restrict__ alpha, const __hip_bfloat16* __restrict__ h,
                      const float* __restrict__ out_prev, const float* __restrict__ bias,
                      __hip_bfloat16* __restrict__ t_out, int use_prev) {
    int d = (blockIdx.x * blockDim.x + threadIdx.x) >> 6;
    int lane = threadIdx.x & 63;
    if (d >= NN) return;
    int s0 = row_ptr[d], s1 = row_ptr[d + 1];
    int deg = s1 - s0;
    int base = lane * 8;
    float acc[8] = {0.f, 0.f, 0.f, 0.f, 0.f, 0.f, 0.f, 0.f};
    for (int j0 = 0; j0 < deg; j0 += 64) {
        int cnt = deg - j0;
        if (cnt > 64) cnt = 64;
        int sv = 0;
        float av = 0.f;
        if (lane < cnt) {
            sv = csr_src[s0 + j0 + lane];
            av = alpha[s0 + j0 + lane];
        }
        for (int t = 0; t < cnt; t++) {
            int s = __shfl(sv, t);
            float a = __shfl(av, t);
            uint4 hv = *(const uint4*)(h + (size_t)s * DD + base);
            const unsigned short* hs = (const unsigned short*)&hv;
#pragma unroll
            for (int k = 0; k < 8; k++) acc[k] += a * bfbits2f(hs[k]);
        }
    }
    if (use_prev) {
        float4 p0 = *(const float4*)(out_prev + (size_t)d * DD + base);
        float4 p1 = *(const float4*)(out_prev + (size_t)d * DD + base + 4);
        acc[0] += p0.x; acc[1] += p0.y; acc[2] += p0.z; acc[3] += p0.w;
        acc[4] += p1.x; acc[5] += p1.y; acc[6] += p1.z; acc[7] += p1.w;
    }
    float4 b0 = *(const float4*)(bias + base);
    float4 b1 = *(const float4*)(bias + base + 4);
    acc[0] += b0.x; acc[1] += b0.y; acc[2] += b0.z; acc[3] += b0.w;
    acc[4] += b1.x; acc[5] += b1.y; acc[6] += b1.z; acc[7] += b1.w;
    union { __hip_bfloat16 b[8]; uint4 u; } cv;
#pragma unroll
    for (int k = 0; k < 8; k++) cv.b[k] = __float2bfloat16(acc[k]);
    *(uint4*)(t_out + (size_t)d * DD + base) = cv.u;
}

extern "C" void kernel_launch(void* const* d_in, const int* in_sizes, int n_in,
                              void* d_out, int out_size, void* d_ws, size_t ws_size,
                              hipStream_t stream) {
    const float* x = (const float*)d_in[0];
    const int* edges[4] = {(const int*)d_in[1], (const int*)d_in[5], (const int*)d_in[9],
                           (const int*)d_in[13]};
    const float* W[4] = {(const float*)d_in[2], (const float*)d_in[6], (const float*)d_in[10],
                         (const float*)d_in[14]};
    const float* al[4] = {(const float*)d_in[3], (const float*)d_in[7], (const float*)d_in[11],
                          (const float*)d_in[15]};
    const float* ar[4] = {(const float*)d_in[4], (const float*)d_in[8], (const float*)d_in[12],
                          (const float*)d_in[16]};
    const float* Wl = (const float*)d_in[17];
    const float* bias = (const float*)d_in[18];
    float* out = (float*)d_out;

    char* w = (char*)d_ws;
    auto alloc = [&](size_t bytes) {
        char* p = w;
        w += (bytes + 255) & ~(size_t)255;
        return p;
    };
    __hip_bfloat16* x_bf = (__hip_bfloat16*)alloc((size_t)NN * DD * 2);
    __hip_bfloat16* h_bf = (__hip_bfloat16*)alloc((size_t)NN * DD * 2);
    __hip_bfloat16* t_bf = (__hip_bfloat16*)alloc((size_t)NN * DD * 2);
    float* xWl = (float*)alloc((size_t)NN * DD * 4);
    __hip_bfloat16* Wt[4];
    for (int i = 0; i < 4; i++) Wt[i] = (__hip_bfloat16*)alloc((size_t)DD * DD * 2);
    __hip_bfloat16* WlTt = (__hip_bfloat16*)alloc((size_t)DD * DD * 2);
    __hip_bfloat16* WlTb = (__hip_bfloat16*)alloc((size_t)DD * DD * 2);
    float* el = (float*)alloc((size_t)NN * 4);
    float* er = (float*)alloc((size_t)NN * 4);
    int* deg = (int*)alloc((size_t)NN * 4);
    int* row_ptr = (int*)alloc((size_t)(NN + 1) * 4);
    int* cursor = (int*)alloc((size_t)NN * 4);
    int* csr_src = (int*)alloc((size_t)EE * 4);
    float* alphaw = (float*)alloc((size_t)EE * 4);

    // one-time preprocessing
    k_convert_bf16<<<(NN * DD / 4 + 255) / 256, 256, 0, stream>>>(x, x_bf, NN * DD / 4);
    dim3 tb(32, 32), tg(16, 16);
    for (int i = 0; i < 4; i++) k_transpose_bf16<<<tg, tb, 0, stream>>>(W[i], Wt[i]);
    k_transpose_bf16<<<tg, tb, 0, stream>>>(Wl, WlTt);
    k_transpose_bf16<<<tg, tb, 0, stream>>>(Wl + 512 * 512, WlTb);

    dim3 gg((NN + 63) / 64, 4);
    // xWl = x @ Wl_top (loop-invariant)
    k_gemm<<<gg, 256, 0, stream>>>(x_bf, WlTt, xWl, nullptr, nullptr, NN, 2);

    for (int i = 0; i < 4; i++) {
        // h = x @ W_i (bf16 out)
        k_gemm<<<gg, 256, 0, stream>>>(x_bf, Wt[i], nullptr, h_bf, nullptr, NN, 0);
        k_el_er<<<NN / 4, 256, 0, stream>>>(h_bf, al[i], ar[i], el, er);
        // CSR build
        k_zero_i32<<<(NN + 255) / 256, 256, 0, stream>>>(deg, NN);
        k_count<<<(EE + 255) / 256, 256, 0, stream>>>(edges[i], deg);
        k_scan<<<1, 1024, 0, stream>>>(deg, row_ptr, cursor);
        k_scatter<<<(EE + 255) / 256, 256, 0, stream>>>(edges[i], cursor, csr_src);
        // edge softmax (wave per dst)
        k_alpha_wave<<<(NN * 64 + 255) / 256, 256, 0, stream>>>(row_ptr, csr_src, el, er, alphaw);
        // aggregate + prev + bias -> t (bf16), wave per dst
        k_aggregate_wave<<<(NN * 64 + 255) / 256, 256, 0, stream>>>(row_ptr, csr_src, alphaw, h_bf,
                                                                    out, bias, t_bf, i > 0 ? 1 : 0);
        // out = relu(xWl + t @ Wl_bot)
        k_gemm<<<gg, 256, 0, stream>>>(t_bf, WlTb, out, nullptr, xWl, NN, 1);
    }
}

// Round 4
// 795.439 us; speedup vs baseline: 1.3151x; 1.1325x over previous
//
#include <hip/hip_runtime.h>
#include <hip/hip_bf16.h>

#define NN 20000
#define DD 512
#define EE 150000

typedef __attribute__((ext_vector_type(8))) short short8;
typedef __attribute__((ext_vector_type(4))) float floatx4;

static __device__ __forceinline__ float bfbits2f(unsigned short u) {
    unsigned int x = ((unsigned int)u) << 16;
    return __uint_as_float(x);
}

#define GLOAD_LDS16(g, l)                                                        \
    __builtin_amdgcn_global_load_lds((const __attribute__((address_space(1))) void*)(g), \
                                     (__attribute__((address_space(3))) void*)(l), 16, 0, 0)

// ---------------- convert fp32 -> bf16 ----------------
__global__ __launch_bounds__(256) void k_convert_bf16(const float* __restrict__ in,
                                                      __hip_bfloat16* __restrict__ out, int n4) {
    int i = blockIdx.x * blockDim.x + threadIdx.x;
    if (i >= n4) return;
    float4 v = ((const float4*)in)[i];
    union { __hip_bfloat16 b[4]; ushort4 u; } cv;
    cv.b[0] = __float2bfloat16(v.x);
    cv.b[1] = __float2bfloat16(v.y);
    cv.b[2] = __float2bfloat16(v.z);
    cv.b[3] = __float2bfloat16(v.w);
    *(ushort4*)(out + 4l * i) = cv.u;
}

// ---------------- 512x512 transpose + convert to bf16 ----------------
__global__ __launch_bounds__(1024) void k_transpose_bf16(const float* __restrict__ in,
                                                         __hip_bfloat16* __restrict__ out) {
    __shared__ float tile[32][33];
    int bx = blockIdx.x * 32;
    int by = blockIdx.y * 32;
    int tx = threadIdx.x, ty = threadIdx.y;
    tile[ty][tx] = in[(by + ty) * 512 + bx + tx];
    __syncthreads();
    out[(bx + ty) * 512 + by + tx] = __float2bfloat16(tile[tx][ty]);
}

// ---------------- bf16 MFMA GEMM: C[M,512] = A[M,512] @ B ----------------
// TM=128 x TN=64 tile, BK=128 (4 phases) to cut barrier-drain count 4x vs
// round-3's BK=32 (latency-serialized at 51us regardless of traffic).
// Per phase: 12x16B global_load_lds per thread in one burst, then 4 MFMA
// k-steps from LDS. 48KB LDS -> 3 blocks/CU. Lane-linear LDS (conflict-free,
// verified SQ_LDS_BANK_CONFLICT=0 rounds 2-3).
// mode 0: Cb = bf16(C). mode 1: Cf = relu(C + bf16 addend).
__global__ __launch_bounds__(256)
void k_gemm(const __hip_bfloat16* __restrict__ A, const __hip_bfloat16* __restrict__ Bt,
            float* __restrict__ Cf, __hip_bfloat16* __restrict__ Cb,
            const __hip_bfloat16* __restrict__ addend, int M, int mode) {
    __shared__ __hip_bfloat16 As[128 * 128];  // 32 KB; 16B-block i = [q=i>>7][r=i&127]
    __shared__ __hip_bfloat16 Bs[64 * 128];   // 16 KB; 16B-block i = [q=i>>6][r=i&63]
    const int tid = threadIdx.x;
    const int lane = tid & 63;
    const int wave = tid >> 6;
    const int row0 = blockIdx.x * 128;
    const int col0 = blockIdx.y * 64;
    const int wm = wave * 32;  // wave rows
    const int q8 = lane >> 4;
    const int l15 = lane & 15;

    // A staging: instr j (0..7) covers 16B-block j*256+tid
    int ar = row0 + (tid & 127);
    if (ar >= M) ar = M - 1;
    const __hip_bfloat16* aptr = A + (size_t)ar * DD + (tid >> 7) * 8;
    __hip_bfloat16* alds = As + (size_t)tid * 8;
    // B staging: instr j (0..3) covers 16B-block j*256+tid
    const __hip_bfloat16* bptr = Bt + (size_t)(col0 + (tid & 63)) * DD + (tid >> 6) * 8;
    __hip_bfloat16* blds = Bs + (size_t)tid * 8;

    floatx4 acc[2][4];
#pragma unroll
    for (int a = 0; a < 2; a++)
#pragma unroll
        for (int b = 0; b < 4; b++) acc[a][b] = (floatx4){0.f, 0.f, 0.f, 0.f};

    for (int p = 0; p < 4; p++) {
        const int k0 = p * 128;
        __syncthreads();
#pragma unroll
        for (int j = 0; j < 8; j++)  // A: q advances by 2 per instr (+16 elems)
            GLOAD_LDS16(aptr + k0 + j * 16, alds + (size_t)j * 256 * 8);
#pragma unroll
        for (int j = 0; j < 4; j++)  // B: q advances by 4 per instr (+32 elems)
            GLOAD_LDS16(bptr + k0 + j * 32, blds + (size_t)j * 256 * 8);
        __syncthreads();
#pragma unroll
        for (int kk = 0; kk < 4; kk++) {
            short8 af[2], bf[4];
#pragma unroll
            for (int mi = 0; mi < 2; mi++)
                af[mi] = *(const short8*)(As + ((size_t)(kk * 4 + q8) * 128 + wm + mi * 16 + l15) * 8);
#pragma unroll
            for (int ni = 0; ni < 4; ni++)
                bf[ni] = *(const short8*)(Bs + ((size_t)(kk * 4 + q8) * 64 + ni * 16 + l15) * 8);
#pragma unroll
            for (int mi = 0; mi < 2; mi++)
#pragma unroll
                for (int ni = 0; ni < 4; ni++)
                    acc[mi][ni] =
                        __builtin_amdgcn_mfma_f32_16x16x32_bf16(af[mi], bf[ni], acc[mi][ni], 0, 0, 0);
        }
    }

#pragma unroll
    for (int mi = 0; mi < 2; mi++)
#pragma unroll
        for (int ni = 0; ni < 4; ni++)
#pragma unroll
            for (int r = 0; r < 4; r++) {
                int grow = row0 + wm + mi * 16 + q8 * 4 + r;
                int gcol = col0 + ni * 16 + l15;
                if (grow < M) {
                    float v = acc[mi][ni][r];
                    size_t idx = (size_t)grow * DD + gcol;
                    if (mode == 0) Cb[idx] = __float2bfloat16(v);
                    else {
                        v += bfbits2f(*(const unsigned short*)(addend + idx));
                        Cf[idx] = v > 0.f ? v : 0.f;
                    }
                }
            }
}

// ---------------- el/er: per-row dot products ----------------
__global__ __launch_bounds__(256)
void k_el_er(const __hip_bfloat16* __restrict__ h, const float* __restrict__ al,
             const float* __restrict__ ar, float* __restrict__ el, float* __restrict__ er) {
    int wave = threadIdx.x >> 6, lane = threadIdx.x & 63;
    int row = blockIdx.x * 4 + wave;
    if (row >= NN) return;
    uint4 hv = *(const uint4*)(h + (size_t)row * 512 + lane * 8);
    const unsigned short* hs = (const unsigned short*)&hv;
    float4 a0 = *(const float4*)(al + lane * 8);
    float4 a1 = *(const float4*)(al + lane * 8 + 4);
    float4 r0 = *(const float4*)(ar + lane * 8);
    float4 r1 = *(const float4*)(ar + lane * 8 + 4);
    float hf[8];
#pragma unroll
    for (int j = 0; j < 8; j++) hf[j] = bfbits2f(hs[j]);
    float sl = hf[0] * a0.x + hf[1] * a0.y + hf[2] * a0.z + hf[3] * a0.w +
               hf[4] * a1.x + hf[5] * a1.y + hf[6] * a1.z + hf[7] * a1.w;
    float sr = hf[0] * r0.x + hf[1] * r0.y + hf[2] * r0.z + hf[3] * r0.w +
               hf[4] * r1.x + hf[5] * r1.y + hf[6] * r1.z + hf[7] * r1.w;
#pragma unroll
    for (int off = 32; off > 0; off >>= 1) {
        sl += __shfl_down(sl, off);
        sr += __shfl_down(sr, off);
    }
    if (lane == 0) {
        el[row] = sl;
        er[row] = sr;
    }
}

// ---------------- CSR build (batched over 4 relations, hoisted pre-loop) ----------------
__global__ void k_zero_i32(int* p, int n) {
    int i = blockIdx.x * blockDim.x + threadIdx.x;
    if (i < n) p[i] = 0;
}

__global__ void k_count4(const int* __restrict__ e0, const int* __restrict__ e1,
                         const int* __restrict__ e2, const int* __restrict__ e3,
                         int* __restrict__ deg4) {
    int g = blockIdx.x * blockDim.x + threadIdx.x;
    if (g >= 4 * EE) return;
    int rel = g / EE;
    int e = g - rel * EE;
    const int* ed = rel == 0 ? e0 : rel == 1 ? e1 : rel == 2 ? e2 : e3;
    atomicAdd(&deg4[rel * NN + ed[EE + e]], 1);
}

__global__ __launch_bounds__(1024)
void k_scan4(const int* __restrict__ deg4, int* __restrict__ rp4, int* __restrict__ cur4) {
    const int rel = blockIdx.x;
    const int* deg = deg4 + rel * NN;
    int* row_ptr = rp4 + rel * (NN + 1);
    int* cursor = cur4 + rel * NN;
    __shared__ int sm[1024];
    int t = threadIdx.x;
    const int CH = 20;
    int begin = t * CH;
    int end = begin + CH;
    if (end > NN) end = NN;
    int s = 0;
    if (begin < NN)
        for (int i = begin; i < end; i++) s += deg[i];
    sm[t] = s;
    __syncthreads();
    for (int off = 1; off < 1024; off <<= 1) {
        int v = (t >= off) ? sm[t - off] : 0;
        __syncthreads();
        sm[t] += v;
        __syncthreads();
    }
    int run = sm[t] - s;
    if (begin < NN) {
        for (int i = begin; i < end; i++) {
            row_ptr[i] = run;
            cursor[i] = run;
            run += deg[i];
        }
        if (end == NN) row_ptr[NN] = run;
    }
}

__global__ void k_scatter4(const int* __restrict__ e0, const int* __restrict__ e1,
                           const int* __restrict__ e2, const int* __restrict__ e3,
                           int* __restrict__ cur4, int* __restrict__ csr4) {
    int g = blockIdx.x * blockDim.x + threadIdx.x;
    if (g >= 4 * EE) return;
    int rel = g / EE;
    int e = g - rel * EE;
    const int* ed = rel == 0 ? e0 : rel == 1 ? e1 : rel == 2 ? e2 : e3;
    int dst = ed[EE + e];
    int pos = atomicAdd(&cur4[rel * NN + dst], 1);
    csr4[rel * EE + pos] = ed[e];
}

// ---------------- fused edge-softmax + aggregate, wave per dst ----------------
// t[dst] = sum_j alpha_j * h[src_j]  (+ out_prev) + bias, written bf16.
// deg<=64: whole softmax in registers via shuffles (no alpha round-trip).
__global__ __launch_bounds__(256)
void k_agg_fused(const int* __restrict__ row_ptr, const int* __restrict__ csr_src,
                 const float* __restrict__ el, const float* __restrict__ er,
                 const __hip_bfloat16* __restrict__ h, const float* __restrict__ out_prev,
                 const float* __restrict__ bias, __hip_bfloat16* __restrict__ t_out,
                 float* __restrict__ alpha_tmp, int use_prev) {
    int d = (blockIdx.x * blockDim.x + threadIdx.x) >> 6;
    int lane = threadIdx.x & 63;
    if (d >= NN) return;
    int s0 = row_ptr[d], s1 = row_ptr[d + 1];
    int deg = s1 - s0;
    int base = lane * 8;
    float acc[8] = {0.f, 0.f, 0.f, 0.f, 0.f, 0.f, 0.f, 0.f};

    if (deg <= 64) {
        int sv = 0;
        float av = 0.f;
        if (lane < deg) sv = csr_src[s0 + lane];
        float erd = er[d];
        float v = -1e30f;
        if (lane < deg) {
            float e = el[sv] + erd;
            v = e >= 0.f ? e : 0.2f * e;
        }
        float m = v;
#pragma unroll
        for (int off = 32; off > 0; off >>= 1) m = fmaxf(m, __shfl_xor(m, off));
        float wgt = (lane < deg) ? __expf(v - m) : 0.f;
        float s = wgt;
#pragma unroll
        for (int off = 32; off > 0; off >>= 1) s += __shfl_xor(s, off);
        av = wgt / s;  // NaN only when deg==0 (never broadcast)
        int t = 0;
        for (; t + 1 < deg; t += 2) {
            int sA = __shfl(sv, t), sB = __shfl(sv, t + 1);
            float aA = __shfl(av, t), aB = __shfl(av, t + 1);
            uint4 hv0 = *(const uint4*)(h + (size_t)sA * DD + base);
            uint4 hv1 = *(const uint4*)(h + (size_t)sB * DD + base);
            const unsigned short* h0 = (const unsigned short*)&hv0;
            const unsigned short* h1 = (const unsigned short*)&hv1;
#pragma unroll
            for (int k = 0; k < 8; k++) acc[k] += aA * bfbits2f(h0[k]) + aB * bfbits2f(h1[k]);
        }
        if (t < deg) {
            int sA = __shfl(sv, t);
            float aA = __shfl(av, t);
            uint4 hv0 = *(const uint4*)(h + (size_t)sA * DD + base);
            const unsigned short* h0 = (const unsigned short*)&hv0;
#pragma unroll
            for (int k = 0; k < 8; k++) acc[k] += aA * bfbits2f(h0[k]);
        }
    } else {
        // rare fallback (Poisson(7.5) makes deg>64 ~never): two-pass via global
        float erd = er[d];
        float m = -1e30f;
        for (int j = s0 + lane; j < s1; j += 64) {
            float e = el[csr_src[j]] + erd;
            e = e >= 0.f ? e : 0.2f * e;
            alpha_tmp[j] = e;
            m = fmaxf(m, e);
        }
#pragma unroll
        for (int off = 32; off > 0; off >>= 1) m = fmaxf(m, __shfl_xor(m, off));
        float s = 0.f;
        for (int j = s0 + lane; j < s1; j += 64) {
            float wv = __expf(alpha_tmp[j] - m);
            alpha_tmp[j] = wv;
            s += wv;
        }
#pragma unroll
        for (int off = 32; off > 0; off >>= 1) s += __shfl_xor(s, off);
        float inv = 1.f / s;
        for (int j0 = 0; j0 < deg; j0 += 64) {
            int cnt = deg - j0;
            if (cnt > 64) cnt = 64;
            int sv = 0;
            float av = 0.f;
            if (lane < cnt) {
                sv = csr_src[s0 + j0 + lane];
                av = alpha_tmp[s0 + j0 + lane] * inv;
            }
            for (int t = 0; t < cnt; t++) {
                int sA = __shfl(sv, t);
                float aA = __shfl(av, t);
                uint4 hv0 = *(const uint4*)(h + (size_t)sA * DD + base);
                const unsigned short* h0 = (const unsigned short*)&hv0;
#pragma unroll
                for (int k = 0; k < 8; k++) acc[k] += aA * bfbits2f(h0[k]);
            }
        }
    }

    if (use_prev) {
        float4 p0 = *(const float4*)(out_prev + (size_t)d * DD + base);
        float4 p1 = *(const float4*)(out_prev + (size_t)d * DD + base + 4);
        acc[0] += p0.x; acc[1] += p0.y; acc[2] += p0.z; acc[3] += p0.w;
        acc[4] += p1.x; acc[5] += p1.y; acc[6] += p1.z; acc[7] += p1.w;
    }
    float4 b0 = *(const float4*)(bias + base);
    float4 b1 = *(const float4*)(bias + base + 4);
    acc[0] += b0.x; acc[1] += b0.y; acc[2] += b0.z; acc[3] += b0.w;
    acc[4] += b1.x; acc[5] += b1.y; acc[6] += b1.z; acc[7] += b1.w;
    union { __hip_bfloat16 b[8]; uint4 u; } cv;
#pragma unroll
    for (int k = 0; k < 8; k++) cv.b[k] = __float2bfloat16(acc[k]);
    *(uint4*)(t_out + (size_t)d * DD + base) = cv.u;
}

extern "C" void kernel_launch(void* const* d_in, const int* in_sizes, int n_in,
                              void* d_out, int out_size, void* d_ws, size_t ws_size,
                              hipStream_t stream) {
    const float* x = (const float*)d_in[0];
    const int* edges[4] = {(const int*)d_in[1], (const int*)d_in[5], (const int*)d_in[9],
                           (const int*)d_in[13]};
    const float* W[4] = {(const float*)d_in[2], (const float*)d_in[6], (const float*)d_in[10],
                         (const float*)d_in[14]};
    const float* al[4] = {(const float*)d_in[3], (const float*)d_in[7], (const float*)d_in[11],
                          (const float*)d_in[15]};
    const float* ar[4] = {(const float*)d_in[4], (const float*)d_in[8], (const float*)d_in[12],
                          (const float*)d_in[16]};
    const float* Wl = (const float*)d_in[17];
    const float* bias = (const float*)d_in[18];
    float* out = (float*)d_out;

    char* w = (char*)d_ws;
    auto alloc = [&](size_t bytes) {
        char* p = w;
        w += (bytes + 255) & ~(size_t)255;
        return p;
    };
    __hip_bfloat16* x_bf = (__hip_bfloat16*)alloc((size_t)NN * DD * 2);
    __hip_bfloat16* h_bf = (__hip_bfloat16*)alloc((size_t)NN * DD * 2);
    __hip_bfloat16* t_bf = (__hip_bfloat16*)alloc((size_t)NN * DD * 2);
    __hip_bfloat16* xwl_bf = (__hip_bfloat16*)alloc((size_t)NN * DD * 2);
    __hip_bfloat16* Wt[4];
    for (int i = 0; i < 4; i++) Wt[i] = (__hip_bfloat16*)alloc((size_t)DD * DD * 2);
    __hip_bfloat16* WlTt = (__hip_bfloat16*)alloc((size_t)DD * DD * 2);
    __hip_bfloat16* WlTb = (__hip_bfloat16*)alloc((size_t)DD * DD * 2);
    float* el = (float*)alloc((size_t)NN * 4);
    float* er = (float*)alloc((size_t)NN * 4);
    int* deg4 = (int*)alloc((size_t)4 * NN * 4);
    int* rp4 = (int*)alloc((size_t)4 * (NN + 1) * 4);
    int* cur4 = (int*)alloc((size_t)4 * NN * 4);
    int* csr4 = (int*)alloc((size_t)4 * EE * 4);
    float* alpha_tmp = (float*)alloc((size_t)EE * 4);

    // preprocessing
    k_convert_bf16<<<(NN * DD / 4 + 255) / 256, 256, 0, stream>>>(x, x_bf, NN * DD / 4);
    dim3 tb(32, 32), tg(16, 16);
    for (int i = 0; i < 4; i++) k_transpose_bf16<<<tg, tb, 0, stream>>>(W[i], Wt[i]);
    k_transpose_bf16<<<tg, tb, 0, stream>>>(Wl, WlTt);
    k_transpose_bf16<<<tg, tb, 0, stream>>>(Wl + 512 * 512, WlTb);

    // CSR for all 4 relations (edges-only, hoisted)
    k_zero_i32<<<(4 * NN + 255) / 256, 256, 0, stream>>>(deg4, 4 * NN);
    k_count4<<<(4 * EE + 255) / 256, 256, 0, stream>>>(edges[0], edges[1], edges[2], edges[3], deg4);
    k_scan4<<<4, 1024, 0, stream>>>(deg4, rp4, cur4);
    k_scatter4<<<(4 * EE + 255) / 256, 256, 0, stream>>>(edges[0], edges[1], edges[2], edges[3],
                                                         cur4, csr4);

    dim3 gg((NN + 127) / 128, 8);
    // xwl = bf16(x @ Wl_top) (loop-invariant addend)
    k_gemm<<<gg, 256, 0, stream>>>(x_bf, WlTt, nullptr, xwl_bf, nullptr, NN, 0);

    for (int i = 0; i < 4; i++) {
        k_gemm<<<gg, 256, 0, stream>>>(x_bf, Wt[i], nullptr, h_bf, nullptr, NN, 0);
        k_el_er<<<NN / 4, 256, 0, stream>>>(h_bf, al[i], ar[i], el, er);
        k_agg_fused<<<(NN * 64 + 255) / 256, 256, 0, stream>>>(
            rp4 + i * (NN + 1), csr4 + (size_t)i * EE, el, er, h_bf, out, bias, t_bf, alpha_tmp,
            i > 0 ? 1 : 0);
        // out = relu(xwl + t @ Wl_bot)
        k_gemm<<<gg, 256, 0, stream>>>(t_bf, WlTb, out, nullptr, xwl_bf, NN, 1);
    }
}